// Round 3
// baseline (226.161 us; speedup 1.0000x reference)
//
#include <hip/hip_runtime.h>
#include <math.h>

// Elementwise B-spline (KAN-style) activation:
//   out = bw * silu(x) + sw * lerp(s[il], s[il+1], frac)
// s[g] = dot(basis_values[g,:], control_points)  (G=3 scalars; linearity of
// the einsum folds the NUM_CP=5 dot into 3 uniform scalars).
//
// Streaming kernel: 2x float4 per thread (block-strided, fully coalesced),
// nontemporal load/store (data is touched exactly once), uniform scalars
// forced into SGPRs via readfirstlane.

typedef float vf4 __attribute__((ext_vector_type(4)));  // native vec for nontemporal builtins

__device__ __forceinline__ float rfl(float v) {
    return __int_as_float(__builtin_amdgcn_readfirstlane(__float_as_int(v)));
}

__device__ __forceinline__ float bspline_elem(float x, float s0, float s1, float s2,
                                              float d0, float d1, float bw, float sw) {
    // grid_idx = (clamp(x,-1,1) - lo)/(hi-lo) * (G-1) = clamp(x,-1,1) + 1
    float t  = fminf(fmaxf(x, -1.0f), 1.0f) + 1.0f;   // in [0,2] exactly
    float fl = floorf(t);
    float fr = t - fl;                                 // frac; 0 when fl==2
    int   il = (int)fl;                                // 0,1,2
    float sl = (il == 0) ? s0 : ((il == 1) ? s1 : s2);
    float dl = (il == 0) ? d0 : d1;                    // il==2 -> fr==0 (exact)
    float y  = sl + fr * dl;
    float sig = 1.0f / (1.0f + __expf(-x));
    return bw * (x * sig) + sw * y;
}

__global__ __launch_bounds__(256) void bspline_act_v8(
    const vf4* __restrict__ x4,
    const float*  __restrict__ cp,    // [5]
    const float*  __restrict__ bw_p,  // [1]
    const float*  __restrict__ sw_p,  // [1]
    const float*  __restrict__ bv,    // [3][5] row-major
    vf4*       __restrict__ out4,
    int n4)
{
    // Uniform scalar precompute, forced to SGPRs.
    const float c0 = cp[0], c1 = cp[1], c2 = cp[2], c3 = cp[3], c4 = cp[4];
    float s0 = bv[0]*c0  + bv[1]*c1  + bv[2]*c2  + bv[3]*c3  + bv[4]*c4;
    float s1 = bv[5]*c0  + bv[6]*c1  + bv[7]*c2  + bv[8]*c3  + bv[9]*c4;
    float s2 = bv[10]*c0 + bv[11]*c1 + bv[12]*c2 + bv[13]*c3 + bv[14]*c4;
    float bw = bw_p[0], sw = sw_p[0];
    s0 = rfl(s0); s1 = rfl(s1); s2 = rfl(s2); bw = rfl(bw); sw = rfl(sw);
    const float d0 = s1 - s0, d1 = s2 - s1;

    const int base = blockIdx.x * 512 + threadIdx.x;   // 2 float4 per thread

#pragma unroll
    for (int u = 0; u < 2; ++u) {
        const int i = base + u * 256;
        if (i < n4) {
            vf4 v = __builtin_nontemporal_load(&x4[i]);
            vf4 r;
            r.x = bspline_elem(v.x, s0, s1, s2, d0, d1, bw, sw);
            r.y = bspline_elem(v.y, s0, s1, s2, d0, d1, bw, sw);
            r.z = bspline_elem(v.z, s0, s1, s2, d0, d1, bw, sw);
            r.w = bspline_elem(v.w, s0, s1, s2, d0, d1, bw, sw);
            __builtin_nontemporal_store(r, &out4[i]);
        }
    }
}

// Scalar tail (n % 4 != 0 — not hit for 8*2048*2048, kept for generality).
__global__ void bspline_act_tail(
    const float* __restrict__ x,
    const float* __restrict__ cp,
    const float* __restrict__ bw_p,
    const float* __restrict__ sw_p,
    const float* __restrict__ bv,
    float*       __restrict__ out,
    int start, int n)
{
    int i = start + blockIdx.x * blockDim.x + threadIdx.x;
    if (i >= n) return;
    const float c0 = cp[0], c1 = cp[1], c2 = cp[2], c3 = cp[3], c4 = cp[4];
    const float s0 = bv[0]*c0  + bv[1]*c1  + bv[2]*c2  + bv[3]*c3  + bv[4]*c4;
    const float s1 = bv[5]*c0  + bv[6]*c1  + bv[7]*c2  + bv[8]*c3  + bv[9]*c4;
    const float s2 = bv[10]*c0 + bv[11]*c1 + bv[12]*c2 + bv[13]*c3 + bv[14]*c4;
    const float d0 = s1 - s0, d1 = s2 - s1;
    const float bw = bw_p[0], sw = sw_p[0];
    out[i] = bspline_elem(x[i], s0, s1, s2, d0, d1, bw, sw);
}

extern "C" void kernel_launch(void* const* d_in, const int* in_sizes, int n_in,
                              void* d_out, int out_size, void* d_ws, size_t ws_size,
                              hipStream_t stream) {
    const float* x  = (const float*)d_in[0];
    const float* cp = (const float*)d_in[1];
    const float* bw = (const float*)d_in[2];
    const float* sw = (const float*)d_in[3];
    const float* bv = (const float*)d_in[4];
    float* out = (float*)d_out;

    const int n  = in_sizes[0];
    const int n4 = n / 4;
    const int rem_start = n4 * 4;

    if (n4 > 0) {
        const int per_block = 256 * 2;                 // 2 float4 per thread
        const int grid = (n4 + per_block - 1) / per_block;
        bspline_act_v8<<<grid, 256, 0, stream>>>(
            (const vf4*)x, cp, bw, sw, bv, (vf4*)out, n4);
    }
    if (rem_start < n) {
        const int rem = n - rem_start;
        bspline_act_tail<<<(rem + 255) / 256, 256, 0, stream>>>(
            x, cp, bw, sw, bv, out, rem_start, n);
    }
}